// Round 5
// baseline (259.544 us; speedup 1.0000x reference)
//
#include <hip/hip_runtime.h>
#include <hip/hip_bf16.h>
#include <stdint.h>

static constexpr int S  = 2048;
static constexpr int NH = 16;
static constexpr int HD = 64;
static constexpr int E  = 1024;
static constexpr int BB = 2;
static constexpr int MR = BB * S;   // 4096 rows

typedef __attribute__((ext_vector_type(8))) short bf16x8;
typedef __attribute__((ext_vector_type(4))) float f32x4;
typedef __attribute__((ext_vector_type(16))) float f32x16;

__device__ __forceinline__ unsigned short f2bf(float f) {
  union { float f; unsigned u; } v; v.f = f;
  unsigned r = v.u + 0x7fffu + ((v.u >> 16) & 1u);
  return (unsigned short)(r >> 16);
}

__device__ __forceinline__ unsigned cvt_pk_bf16(float lo, float hi) {
  unsigned r;
  asm("v_cvt_pk_bf16_f32 %0, %1, %2" : "=v"(r) : "v"(lo), "v"(hi));
  return r;
}

__device__ __forceinline__ f32x4 mfma16(bf16x8 a, bf16x8 b, f32x4 c) {
  return __builtin_amdgcn_mfma_f32_16x16x32_bf16(a, b, c, 0, 0, 0);
}
__device__ __forceinline__ f32x16 mfma32(bf16x8 a, bf16x8 b, f32x16 c) {
  return __builtin_amdgcn_mfma_f32_32x32x16_bf16(a, b, c, 0, 0, 0);
}

__device__ __forceinline__ void gload_lds16(const void* g, void* l) {
  __builtin_amdgcn_global_load_lds(
      (const __attribute__((address_space(1))) uint32_t*)(uintptr_t)g,
      (__attribute__((address_space(3))) uint32_t*)(uintptr_t)l,
      16, 0, 0);
}

__global__ __launch_bounds__(256) void convert_bf16(
    const float* __restrict__ in, unsigned short* __restrict__ out, int n4) {
  int i = blockIdx.x * blockDim.x + threadIdx.x;
  const int stride = gridDim.x * blockDim.x;
  for (; i < n4; i += stride) {
    float4 v = ((const float4*)in)[i];
    ushort4 o;
    o.x = f2bf(v.x); o.y = f2bf(v.y); o.z = f2bf(v.z); o.w = f2bf(v.w);
    ((ushort4*)out)[i] = o;
  }
}

// C = A @ W^T + bias.  A: MxK bf16 row-major, W: NxK bf16 row-major.
// EPI 0: scatter to Q (pre-scaled by 0.125*log2e), K, Vt.  EPI 1: f32 + bias.
template <int EPI>
__global__ __launch_bounds__(256) void gemm_bt(
    const unsigned short* __restrict__ A, const unsigned short* __restrict__ W,
    const float* __restrict__ bias,
    void* __restrict__ o0, void* __restrict__ o1, void* __restrict__ o2,
    int M, int N, int K) {
  __shared__ __align__(16) unsigned short As[128 * 32];
  __shared__ __align__(16) unsigned short Bs[128 * 32];
  const int tid  = threadIdx.x;
  const int lane = tid & 63;
  const int wid  = tid >> 6;
  const int wm   = wid >> 1;
  const int wn   = wid & 1;
  const int g    = lane >> 4;
  const int lq   = lane & 15;
  const int row0 = blockIdx.y * 128;
  const int col0 = blockIdx.x * 128;
  const int srow = lane >> 2;
  const int sseg = (lane & 3) * 8;

  f32x4 acc[4][4] = {};

  for (int k0 = 0; k0 < K; k0 += 32) {
    __syncthreads();
#pragma unroll
    for (int cc = 0; cc < 2; ++cc) {
      const int c = wid + cc * 4;
      gload_lds16(A + (size_t)(row0 + c * 16 + srow) * K + k0 + sseg,
                  (char*)As + c * 1024);
      gload_lds16(W + (size_t)(col0 + c * 16 + srow) * K + k0 + sseg,
                  (char*)Bs + c * 1024);
    }
    __syncthreads();
    bf16x8 af[4], bfr[4];
#pragma unroll
    for (int m = 0; m < 4; ++m)
      af[m] = *(const bf16x8*)(As + (wm * 64 + m * 16 + lq) * 32 + g * 8);
#pragma unroll
    for (int n = 0; n < 4; ++n)
      bfr[n] = *(const bf16x8*)(Bs + (wn * 64 + n * 16 + lq) * 32 + g * 8);
#pragma unroll
    for (int m = 0; m < 4; ++m)
#pragma unroll
      for (int n = 0; n < 4; ++n)
        acc[m][n] = mfma16(af[m], bfr[n], acc[m][n]);
  }

  if (EPI == 0) {
    unsigned short* Qb = (unsigned short*)o0;
    unsigned short* Kb = (unsigned short*)o1;
    unsigned short* Vt = (unsigned short*)o2;
    const float qsc = 0.125f * 1.44269504f;  // fold scale+log2e into Q
#pragma unroll
    for (int m = 0; m < 4; ++m) {
      const int rbase = row0 + wm * 64 + m * 16 + g * 4;
#pragma unroll
      for (int n = 0; n < 4; ++n) {
        const int col = col0 + wn * 64 + n * 16 + lq;
        const float bi = bias[col];
        const int three = col >> 10;
        const int rem = col & 1023;
        const int h = rem >> 6, d = rem & 63;
#pragma unroll
        for (int r = 0; r < 4; ++r) {
          const int row = rbase + r;
          const int bb = row >> 11, ss = row & 2047;
          float val = acc[m][n][r] + bi;
          if (three == 0) val *= qsc;
          const unsigned short bv = f2bf(val);
          if (three == 0)
            Qb[(((size_t)(bb * NH + h)) * S + ss) * HD + d] = bv;
          else if (three == 1)
            Kb[(((size_t)(bb * NH + h)) * S + ss) * HD + d] = bv;
          else
            Vt[(((size_t)(bb * NH + h)) * HD + d) * S + ss] = bv;
        }
      }
    }
  } else {
    float* Out = (float*)o0;
#pragma unroll
    for (int m = 0; m < 4; ++m) {
      const int rbase = row0 + wm * 64 + m * 16 + g * 4;
#pragma unroll
      for (int n = 0; n < 4; ++n) {
        const int col = col0 + wn * 64 + n * 16 + lq;
        const float bi = bias[col];
#pragma unroll
        for (int r = 0; r < 4; ++r)
          Out[(size_t)(rbase + r) * N + col] = acc[m][n][r] + bi;
      }
    }
  }
}

// Flash attention v3: 2 waves x 32 q = 64 q-rows/block, KV tile 64,
// double-buffered LDS w/ raw-barrier pipeline, defer-max softmax.
// Q pre-scaled by 0.125*log2e.  Q,K: (b,h,s,d); Vt: (b,h,d,s); out (b,s,h,d).
__global__ __launch_bounds__(128) void attn_fwd3(
    const unsigned short* __restrict__ Qb, const unsigned short* __restrict__ Kb,
    const unsigned short* __restrict__ Vt, unsigned short* __restrict__ Ao,
    const int* __restrict__ causal_p) {
  __shared__ __align__(16) unsigned short Ks[2][64 * 64];
  __shared__ __align__(16) unsigned short Vs[2][64 * 64];

  const int tid = threadIdx.x, lane = tid & 63, wid = tid >> 6;
  const int cq = lane & 31;
  const int hi = lane >> 5;
  const int id = blockIdx.x;                    // 1024 blocks
  const int swz = (id & 7) * 128 + (id >> 3);   // XCD-contiguous
  const int bh = swz >> 5;                      // 4 bh per XCD
  const int qt = 31 - (swz & 31);               // heavy q-tiles first
  const int causal = *causal_p;
  const size_t base  = (size_t)bh * S * HD;
  const size_t vbase = (size_t)bh * HD * S;
  const int qw = qt * 64 + wid * 32;            // wave's first q row

  bf16x8 qf[4];
#pragma unroll
  for (int f = 0; f < 4; ++f)
    qf[f] = *(const bf16x8*)(Qb + base + (size_t)(qw + cq) * HD + f * 16 + hi * 8);

  float mM = -1e30f, lS = 0.f;
  f32x16 o0 = {}, o1 = {};

  const int r8 = lane >> 3;
  const int ssl = ((lane & 7) ^ r8) * 8;        // pre-swizzled source col (elems)
  const int nkt = causal ? (qt + 1) : (S / 64);

#define STAGE(bufi, kt)                                                        \
  {                                                                            \
    _Pragma("unroll")                                                          \
    for (int i = 0; i < 4; ++i) {                                              \
      const int c = wid * 4 + i;                                               \
      gload_lds16(Kb + base + (size_t)((kt) * 64 + c * 8 + r8) * HD + ssl,     \
                  (char*)Ks[bufi] + c * 1024);                                 \
      gload_lds16(Vt + vbase + (size_t)(c * 8 + r8) * S + (kt) * 64 + ssl,     \
                  (char*)Vs[bufi] + c * 1024);                                 \
    }                                                                          \
  }

  STAGE(0, 0)
  int buf = 0;

  for (int kt = 0; kt < nkt; ++kt) {
    asm volatile("s_waitcnt vmcnt(0)" ::: "memory");
    __builtin_amdgcn_s_barrier();
    if (kt + 1 < nkt) STAGE(buf ^ 1, kt + 1)

    const char* Kp = (const char*)Ks[buf];
    const char* Vp = (const char*)Vs[buf];
    const int swb = (cq & 7) << 4;

    // QK^T swapped: D[k][q]
    f32x16 sc0 = {}, sc1 = {};
    __builtin_amdgcn_s_setprio(1);
#pragma unroll
    for (int df = 0; df < 4; ++df) {
      const int colb = (df * 32 + hi * 16) ^ swb;
      bf16x8 k0 = *(const bf16x8*)(Kp + cq * 128 + colb);
      bf16x8 k1 = *(const bf16x8*)(Kp + (32 + cq) * 128 + colb);
      sc0 = mfma32(k0, qf[df], sc0);
      sc1 = mfma32(k1, qf[df], sc1);
    }
    __builtin_amdgcn_s_setprio(0);

    if (causal && kt == nkt - 1) {   // diagonal tile (only the last one)
      const int q = qw + cq;
      const int kb = kt * 64 + 4 * hi;
#pragma unroll
      for (int r = 0; r < 16; ++r) {
        const int kl = (r & 3) + 8 * (r >> 2);
        if (kb + kl > q)      sc0[r] = -1e30f;
        if (kb + 32 + kl > q) sc1[r] = -1e30f;
      }
    }

    // tile max: 4-way ILP tree
    float m0 = fmaxf(sc0[0], sc1[0]), m1 = fmaxf(sc0[1], sc1[1]);
    float m2 = fmaxf(sc0[2], sc1[2]), m3 = fmaxf(sc0[3], sc1[3]);
#pragma unroll
    for (int r = 4; r < 16; r += 4) {
      m0 = fmaxf(m0, fmaxf(sc0[r],     sc1[r]));
      m1 = fmaxf(m1, fmaxf(sc0[r + 1], sc1[r + 1]));
      m2 = fmaxf(m2, fmaxf(sc0[r + 2], sc1[r + 2]));
      m3 = fmaxf(m3, fmaxf(sc0[r + 3], sc1[r + 3]));
    }
    float mx = fmaxf(fmaxf(m0, m1), fmaxf(m2, m3));
    mx = fmaxf(mx, __shfl_xor(mx, 32));

    // defer-max: rescale only when the running max grew by > 8 (log2 units)
    if (__any(mx > mM + 8.0f)) {
      const float mnew = fmaxf(mM, mx);
      const float al = exp2f(mM - mnew);
      mM = mnew;
      lS *= al; o0 *= al; o1 *= al;
    }

    // P = exp2(sc - mM), row-sum with 4-way chains
    float r0 = 0.f, r1 = 0.f, r2 = 0.f, r3 = 0.f;
#pragma unroll
    for (int r = 0; r < 16; r += 4) {
      sc0[r]     = exp2f(sc0[r]     - mM); sc1[r]     = exp2f(sc1[r]     - mM);
      sc0[r + 1] = exp2f(sc0[r + 1] - mM); sc1[r + 1] = exp2f(sc1[r + 1] - mM);
      sc0[r + 2] = exp2f(sc0[r + 2] - mM); sc1[r + 2] = exp2f(sc1[r + 2] - mM);
      sc0[r + 3] = exp2f(sc0[r + 3] - mM); sc1[r + 3] = exp2f(sc1[r + 3] - mM);
      r0 += sc0[r]     + sc1[r];
      r1 += sc0[r + 1] + sc1[r + 1];
      r2 += sc0[r + 2] + sc1[r + 2];
      r3 += sc0[r + 3] + sc1[r + 3];
    }
    float rs = (r0 + r1) + (r2 + r3);
    rs += __shfl_xor(rs, 32);
    lS += rs;

    // pack P to bf16 pairs
    unsigned w[16];
#pragma unroll
    for (int i = 0; i < 8; ++i) {
      w[i]     = cvt_pk_bf16(sc0[2 * i], sc0[2 * i + 1]);
      w[i + 8] = cvt_pk_bf16(sc1[2 * i], sc1[2 * i + 1]);
    }

    // PV swapped: O^T += Vt·P
#pragma unroll
    for (int m = 0; m < 4; ++m) {
      const unsigned a = w[4 * m], b = w[4 * m + 1], c = w[4 * m + 2], d = w[4 * m + 3];
      const unsigned ra = __shfl_xor((int)(hi ? a : c), 32);
      const unsigned rb = __shfl_xor((int)(hi ? b : d), 32);
      union { unsigned u[4]; bf16x8 v; } pf;
      pf.u[0] = hi ? ra : a;
      pf.u[1] = hi ? rb : b;
      pf.u[2] = hi ? c : ra;
      pf.u[3] = hi ? d : rb;
      const int colb = (m * 32 + hi * 16) ^ swb;
      bf16x8 v0 = *(const bf16x8*)(Vp + cq * 128 + colb);
      bf16x8 v1 = *(const bf16x8*)(Vp + (32 + cq) * 128 + colb);
      __builtin_amdgcn_s_setprio(1);
      o0 = mfma32(v0, pf.v, o0);
      o1 = mfma32(v1, pf.v, o1);
      __builtin_amdgcn_s_setprio(0);
    }
    buf ^= 1;
  }
#undef STAGE

  // epilogue: O[q][d] = O^T/lS, write (b, s, h, d)
  const int bb2 = bh >> 4, hh = bh & 15;
  unsigned short* orow = Ao + (((size_t)bb2 * S + (qw + cq)) * NH + hh) * HD;
  const float inv = 1.0f / lS;
#pragma unroll
  for (int i = 0; i < 4; ++i) {
    ushort4 u0, u1;
    u0.x = f2bf(o0[4 * i + 0] * inv); u0.y = f2bf(o0[4 * i + 1] * inv);
    u0.z = f2bf(o0[4 * i + 2] * inv); u0.w = f2bf(o0[4 * i + 3] * inv);
    u1.x = f2bf(o1[4 * i + 0] * inv); u1.y = f2bf(o1[4 * i + 1] * inv);
    u1.z = f2bf(o1[4 * i + 2] * inv); u1.w = f2bf(o1[4 * i + 3] * inv);
    *(ushort4*)(orow + i * 8 + 4 * hi) = u0;
    *(ushort4*)(orow + 32 + i * 8 + 4 * hi) = u1;
  }
}

extern "C" void kernel_launch(void* const* d_in, const int* in_sizes, int n_in,
                              void* d_out, int out_size, void* d_ws, size_t ws_size,
                              hipStream_t stream) {
  const float* x     = (const float*)d_in[0];
  const float* w_qkv = (const float*)d_in[1];
  const float* b_qkv = (const float*)d_in[2];
  const float* w_out = (const float*)d_in[3];
  const float* b_out = (const float*)d_in[4];
  const int*   causal = (const int*)d_in[5];

  char* ws = (char*)d_ws;
  unsigned short* xb    = (unsigned short*)(ws);
  unsigned short* wqkvb = (unsigned short*)(ws + 8388608);
  unsigned short* wob   = (unsigned short*)(ws + 14680064);
  unsigned short* Qb    = (unsigned short*)(ws + 16777216);
  unsigned short* Kb    = (unsigned short*)(ws + 25165824);
  unsigned short* Vtb   = (unsigned short*)(ws + 33554432);
  unsigned short* attnb = (unsigned short*)(ws + 41943040);

  convert_bf16<<<1024, 256, 0, stream>>>(x, xb, (BB * S * E) / 4);
  convert_bf16<<<1024, 256, 0, stream>>>(w_qkv, wqkvb, (3 * E * E) / 4);
  convert_bf16<<<512, 256, 0, stream>>>(w_out, wob, (E * E) / 4);

  gemm_bt<0><<<dim3(3 * E / 128, MR / 128), 256, 0, stream>>>(
      xb, wqkvb, b_qkv, Qb, Kb, Vtb, MR, 3 * E, E);

  attn_fwd3<<<1024, 128, 0, stream>>>(Qb, Kb, Vtb, attnb, causal);

  gemm_bt<1><<<dim3(E / 128, MR / 128), 256, 0, stream>>>(
      attnb, wob, b_out, d_out, nullptr, nullptr, MR, E, E);
}

// Round 6
// 255.590 us; speedup vs baseline: 1.0155x; 1.0155x over previous
//
#include <hip/hip_runtime.h>
#include <hip/hip_bf16.h>
#include <stdint.h>

static constexpr int S  = 2048;
static constexpr int NH = 16;
static constexpr int HD = 64;
static constexpr int E  = 1024;
static constexpr int BB = 2;
static constexpr int MR = BB * S;   // 4096 rows

typedef __attribute__((ext_vector_type(8))) short bf16x8;
typedef __attribute__((ext_vector_type(4))) float f32x4;
typedef __attribute__((ext_vector_type(16))) float f32x16;

__device__ __forceinline__ unsigned short f2bf(float f) {
  union { float f; unsigned u; } v; v.f = f;
  unsigned r = v.u + 0x7fffu + ((v.u >> 16) & 1u);
  return (unsigned short)(r >> 16);
}

__device__ __forceinline__ unsigned cvt_pk_bf16(float lo, float hi) {
  unsigned r;
  asm("v_cvt_pk_bf16_f32 %0, %1, %2" : "=v"(r) : "v"(lo), "v"(hi));
  return r;
}

__device__ __forceinline__ f32x4 mfma16(bf16x8 a, bf16x8 b, f32x4 c) {
  return __builtin_amdgcn_mfma_f32_16x16x32_bf16(a, b, c, 0, 0, 0);
}
__device__ __forceinline__ f32x16 mfma32(bf16x8 a, bf16x8 b, f32x16 c) {
  return __builtin_amdgcn_mfma_f32_32x32x16_bf16(a, b, c, 0, 0, 0);
}

__device__ __forceinline__ void gload_lds16(const void* g, void* l) {
  __builtin_amdgcn_global_load_lds(
      (const __attribute__((address_space(1))) uint32_t*)(uintptr_t)g,
      (__attribute__((address_space(3))) uint32_t*)(uintptr_t)l,
      16, 0, 0);
}

__global__ __launch_bounds__(256) void convert_bf16(
    const float* __restrict__ in, unsigned short* __restrict__ out, int n4) {
  int i = blockIdx.x * blockDim.x + threadIdx.x;
  const int stride = gridDim.x * blockDim.x;
  for (; i < n4; i += stride) {
    float4 v = ((const float4*)in)[i];
    ushort4 o;
    o.x = f2bf(v.x); o.y = f2bf(v.y); o.z = f2bf(v.z); o.w = f2bf(v.w);
    ((ushort4*)out)[i] = o;
  }
}

// C = A @ W^T + bias.  A: MxK bf16 row-major, W: NxK bf16 row-major.
// EPI 0: scatter to Q (pre-scaled by 0.125*log2e), K, Vt.  EPI 1: f32 + bias.
template <int EPI>
__global__ __launch_bounds__(256) void gemm_bt(
    const unsigned short* __restrict__ A, const unsigned short* __restrict__ W,
    const float* __restrict__ bias,
    void* __restrict__ o0, void* __restrict__ o1, void* __restrict__ o2,
    int M, int N, int K) {
  __shared__ __align__(16) unsigned short As[128 * 32];
  __shared__ __align__(16) unsigned short Bs[128 * 32];
  const int tid  = threadIdx.x;
  const int lane = tid & 63;
  const int wid  = tid >> 6;
  const int wm   = wid >> 1;
  const int wn   = wid & 1;
  const int g    = lane >> 4;
  const int lq   = lane & 15;
  const int row0 = blockIdx.y * 128;
  const int col0 = blockIdx.x * 128;
  const int srow = lane >> 2;
  const int sseg = (lane & 3) * 8;

  f32x4 acc[4][4] = {};

  for (int k0 = 0; k0 < K; k0 += 32) {
    __syncthreads();
#pragma unroll
    for (int cc = 0; cc < 2; ++cc) {
      const int c = wid + cc * 4;
      gload_lds16(A + (size_t)(row0 + c * 16 + srow) * K + k0 + sseg,
                  (char*)As + c * 1024);
      gload_lds16(W + (size_t)(col0 + c * 16 + srow) * K + k0 + sseg,
                  (char*)Bs + c * 1024);
    }
    __syncthreads();
    bf16x8 af[4], bfr[4];
#pragma unroll
    for (int m = 0; m < 4; ++m)
      af[m] = *(const bf16x8*)(As + (wm * 64 + m * 16 + lq) * 32 + g * 8);
#pragma unroll
    for (int n = 0; n < 4; ++n)
      bfr[n] = *(const bf16x8*)(Bs + (wn * 64 + n * 16 + lq) * 32 + g * 8);
#pragma unroll
    for (int m = 0; m < 4; ++m)
#pragma unroll
      for (int n = 0; n < 4; ++n)
        acc[m][n] = mfma16(af[m], bfr[n], acc[m][n]);
  }

  if (EPI == 0) {
    unsigned short* Qb = (unsigned short*)o0;
    unsigned short* Kb = (unsigned short*)o1;
    unsigned short* Vt = (unsigned short*)o2;
    const float qsc = 0.125f * 1.44269504f;  // fold scale+log2e into Q
#pragma unroll
    for (int m = 0; m < 4; ++m) {
      const int rbase = row0 + wm * 64 + m * 16 + g * 4;
#pragma unroll
      for (int n = 0; n < 4; ++n) {
        const int col = col0 + wn * 64 + n * 16 + lq;
        const float bi = bias[col];
        const int three = col >> 10;
        const int rem = col & 1023;
        const int h = rem >> 6, d = rem & 63;
#pragma unroll
        for (int r = 0; r < 4; ++r) {
          const int row = rbase + r;
          const int bb = row >> 11, ss = row & 2047;
          float val = acc[m][n][r] + bi;
          if (three == 0) val *= qsc;
          const unsigned short bv = f2bf(val);
          if (three == 0)
            Qb[(((size_t)(bb * NH + h)) * S + ss) * HD + d] = bv;
          else if (three == 1)
            Kb[(((size_t)(bb * NH + h)) * S + ss) * HD + d] = bv;
          else
            Vt[(((size_t)(bb * NH + h)) * HD + d) * S + ss] = bv;
        }
      }
    }
  } else {
    float* Out = (float*)o0;
#pragma unroll
    for (int m = 0; m < 4; ++m) {
      const int rbase = row0 + wm * 64 + m * 16 + g * 4;
#pragma unroll
      for (int n = 0; n < 4; ++n) {
        const int col = col0 + wn * 64 + n * 16 + lq;
        const float bi = bias[col];
#pragma unroll
        for (int r = 0; r < 4; ++r)
          Out[(size_t)(rbase + r) * N + col] = acc[m][n][r] + bi;
      }
    }
  }
}

// Flash attention v4: balanced CU packing.
// Block: 2 waves x 32 q = 64 q-rows, KV tile 64, dbuf LDS pipeline, defer-max.
// id decode: XCD x=id&7 gets bh {4x..4x+3} (KV L2-fits); the 4 blocks landing
// on one CU (j=id>>8) have qt {c, 31-c, c+8, 23-c} -> uniform 66 tiles/CU.
__global__ __launch_bounds__(128) void attn_fwd4(
    const unsigned short* __restrict__ Qb, const unsigned short* __restrict__ Kb,
    const unsigned short* __restrict__ Vt, unsigned short* __restrict__ Ao,
    const int* __restrict__ causal_p) {
  __shared__ __align__(16) unsigned short Ks[2][64 * 64];
  __shared__ __align__(16) unsigned short Vs[2][64 * 64];

  const int tid = threadIdx.x, lane = tid & 63, wid = tid >> 6;
  const int cq = lane & 31;
  const int hi = lane >> 5;
  const int id = blockIdx.x;                    // 1024 blocks
  const int x   = id & 7;                       // XCD (round-robin)
  const int c32 = (id >> 3) & 31;               // CU slot within XCD
  const int j   = id >> 8;                      // occupancy round 0..3
  const int bh  = x * 4 + j;
  const int pb  = (c32 + 8 * (j >> 1)) & 31;
  const int qt  = (j & 1) ? (31 - pb) : pb;     // per-CU tile sum = 66
  const int causal = *causal_p;
  const size_t base  = (size_t)bh * S * HD;
  const size_t vbase = (size_t)bh * HD * S;
  const int qw = qt * 64 + wid * 32;            // wave's first q row

  bf16x8 qf[4];
#pragma unroll
  for (int f = 0; f < 4; ++f)
    qf[f] = *(const bf16x8*)(Qb + base + (size_t)(qw + cq) * HD + f * 16 + hi * 8);

  float mM = -1e30f, lS = 0.f;
  f32x16 o0a = {}, o0b = {}, o1a = {}, o1b = {};  // split PV chains (2-deep)

  const int r8 = lane >> 3;
  const int ssl = ((lane & 7) ^ r8) * 8;        // pre-swizzled source col (elems)
  const int nkt = causal ? (qt + 1) : (S / 64);

#define STAGE(bufi, kt)                                                        \
  {                                                                            \
    _Pragma("unroll")                                                          \
    for (int i = 0; i < 4; ++i) {                                              \
      const int c = wid * 4 + i;                                               \
      gload_lds16(Kb + base + (size_t)((kt) * 64 + c * 8 + r8) * HD + ssl,     \
                  (char*)Ks[bufi] + c * 1024);                                 \
      gload_lds16(Vt + vbase + (size_t)(c * 8 + r8) * S + (kt) * 64 + ssl,     \
                  (char*)Vs[bufi] + c * 1024);                                 \
    }                                                                          \
  }

  STAGE(0, 0)
  int buf = 0;

  for (int kt = 0; kt < nkt; ++kt) {
    asm volatile("s_waitcnt vmcnt(0)" ::: "memory");
    __builtin_amdgcn_s_barrier();
    if (kt + 1 < nkt) STAGE(buf ^ 1, kt + 1)

    const char* Kp = (const char*)Ks[buf];
    const char* Vp = (const char*)Vs[buf];
    const int swb = (cq & 7) << 4;

    // QK^T swapped: D[k][q]
    f32x16 sc0 = {}, sc1 = {};
    __builtin_amdgcn_s_setprio(1);
#pragma unroll
    for (int df = 0; df < 4; ++df) {
      const int colb = (df * 32 + hi * 16) ^ swb;
      bf16x8 k0 = *(const bf16x8*)(Kp + cq * 128 + colb);
      bf16x8 k1 = *(const bf16x8*)(Kp + (32 + cq) * 128 + colb);
      sc0 = mfma32(k0, qf[df], sc0);
      sc1 = mfma32(k1, qf[df], sc1);
    }
    __builtin_amdgcn_s_setprio(0);

    if (causal && kt == nkt - 1) {   // diagonal tile (only the last one)
      const int q = qw + cq;
      const int kb = kt * 64 + 4 * hi;
#pragma unroll
      for (int r = 0; r < 16; ++r) {
        const int kl = (r & 3) + 8 * (r >> 2);
        if (kb + kl > q)      sc0[r] = -1e30f;
        if (kb + 32 + kl > q) sc1[r] = -1e30f;
      }
    }

    // tile max: 4-way ILP tree
    float m0 = fmaxf(sc0[0], sc1[0]), m1 = fmaxf(sc0[1], sc1[1]);
    float m2 = fmaxf(sc0[2], sc1[2]), m3 = fmaxf(sc0[3], sc1[3]);
#pragma unroll
    for (int r = 4; r < 16; r += 4) {
      m0 = fmaxf(m0, fmaxf(sc0[r],     sc1[r]));
      m1 = fmaxf(m1, fmaxf(sc0[r + 1], sc1[r + 1]));
      m2 = fmaxf(m2, fmaxf(sc0[r + 2], sc1[r + 2]));
      m3 = fmaxf(m3, fmaxf(sc0[r + 3], sc1[r + 3]));
    }
    float mx = fmaxf(fmaxf(m0, m1), fmaxf(m2, m3));
    mx = fmaxf(mx, __shfl_xor(mx, 32));

    // defer-max: rescale only when the running max grew by > 8 (log2 units)
    if (__any(mx > mM + 8.0f)) {
      const float mnew = fmaxf(mM, mx);
      const float al = exp2f(mM - mnew);
      mM = mnew;
      lS *= al;
      o0a *= al; o0b *= al; o1a *= al; o1b *= al;
    }

    // P = exp2(sc - mM), row-sum with 4-way chains
    float r0 = 0.f, r1 = 0.f, r2 = 0.f, r3 = 0.f;
#pragma unroll
    for (int r = 0; r < 16; r += 4) {
      sc0[r]     = exp2f(sc0[r]     - mM); sc1[r]     = exp2f(sc1[r]     - mM);
      sc0[r + 1] = exp2f(sc0[r + 1] - mM); sc1[r + 1] = exp2f(sc1[r + 1] - mM);
      sc0[r + 2] = exp2f(sc0[r + 2] - mM); sc1[r + 2] = exp2f(sc1[r + 2] - mM);
      sc0[r + 3] = exp2f(sc0[r + 3] - mM); sc1[r + 3] = exp2f(sc1[r + 3] - mM);
      r0 += sc0[r]     + sc1[r];
      r1 += sc0[r + 1] + sc1[r + 1];
      r2 += sc0[r + 2] + sc1[r + 2];
      r3 += sc0[r + 3] + sc1[r + 3];
    }
    float rs = (r0 + r1) + (r2 + r3);
    rs += __shfl_xor(rs, 32);
    lS += rs;

    // pack P to bf16 pairs
    unsigned w[16];
#pragma unroll
    for (int i = 0; i < 8; ++i) {
      w[i]     = cvt_pk_bf16(sc0[2 * i], sc0[2 * i + 1]);
      w[i + 8] = cvt_pk_bf16(sc1[2 * i], sc1[2 * i + 1]);
    }

    // PV swapped: O^T += Vt·P  (m 0,1 -> a-accs; m 2,3 -> b-accs)
#pragma unroll
    for (int m = 0; m < 4; ++m) {
      const unsigned a = w[4 * m], b = w[4 * m + 1], c = w[4 * m + 2], d = w[4 * m + 3];
      const unsigned ra = __shfl_xor((int)(hi ? a : c), 32);
      const unsigned rb = __shfl_xor((int)(hi ? b : d), 32);
      union { unsigned u[4]; bf16x8 v; } pf;
      pf.u[0] = hi ? ra : a;
      pf.u[1] = hi ? rb : b;
      pf.u[2] = hi ? c : ra;
      pf.u[3] = hi ? d : rb;
      const int colb = (m * 32 + hi * 16) ^ swb;
      bf16x8 v0 = *(const bf16x8*)(Vp + cq * 128 + colb);
      bf16x8 v1 = *(const bf16x8*)(Vp + (32 + cq) * 128 + colb);
      __builtin_amdgcn_s_setprio(1);
      if (m < 2) { o0a = mfma32(v0, pf.v, o0a); o1a = mfma32(v1, pf.v, o1a); }
      else       { o0b = mfma32(v0, pf.v, o0b); o1b = mfma32(v1, pf.v, o1b); }
      __builtin_amdgcn_s_setprio(0);
    }
    buf ^= 1;
  }
#undef STAGE

  // epilogue: O[q][d] = (Oa+Ob)/lS, write (b, s, h, d)
  const int bb2 = bh >> 4, hh = bh & 15;
  unsigned short* orow = Ao + (((size_t)bb2 * S + (qw + cq)) * NH + hh) * HD;
  const float inv = 1.0f / lS;
#pragma unroll
  for (int i = 0; i < 4; ++i) {
    ushort4 u0, u1;
    u0.x = f2bf((o0a[4 * i + 0] + o0b[4 * i + 0]) * inv);
    u0.y = f2bf((o0a[4 * i + 1] + o0b[4 * i + 1]) * inv);
    u0.z = f2bf((o0a[4 * i + 2] + o0b[4 * i + 2]) * inv);
    u0.w = f2bf((o0a[4 * i + 3] + o0b[4 * i + 3]) * inv);
    u1.x = f2bf((o1a[4 * i + 0] + o1b[4 * i + 0]) * inv);
    u1.y = f2bf((o1a[4 * i + 1] + o1b[4 * i + 1]) * inv);
    u1.z = f2bf((o1a[4 * i + 2] + o1b[4 * i + 2]) * inv);
    u1.w = f2bf((o1a[4 * i + 3] + o1b[4 * i + 3]) * inv);
    *(ushort4*)(orow + i * 8 + 4 * hi) = u0;
    *(ushort4*)(orow + 32 + i * 8 + 4 * hi) = u1;
  }
}

extern "C" void kernel_launch(void* const* d_in, const int* in_sizes, int n_in,
                              void* d_out, int out_size, void* d_ws, size_t ws_size,
                              hipStream_t stream) {
  const float* x     = (const float*)d_in[0];
  const float* w_qkv = (const float*)d_in[1];
  const float* b_qkv = (const float*)d_in[2];
  const float* w_out = (const float*)d_in[3];
  const float* b_out = (const float*)d_in[4];
  const int*   causal = (const int*)d_in[5];

  char* ws = (char*)d_ws;
  unsigned short* xb    = (unsigned short*)(ws);
  unsigned short* wqkvb = (unsigned short*)(ws + 8388608);
  unsigned short* wob   = (unsigned short*)(ws + 14680064);
  unsigned short* Qb    = (unsigned short*)(ws + 16777216);
  unsigned short* Kb    = (unsigned short*)(ws + 25165824);
  unsigned short* Vtb   = (unsigned short*)(ws + 33554432);
  unsigned short* attnb = (unsigned short*)(ws + 41943040);

  convert_bf16<<<1024, 256, 0, stream>>>(x, xb, (BB * S * E) / 4);
  convert_bf16<<<1024, 256, 0, stream>>>(w_qkv, wqkvb, (3 * E * E) / 4);
  convert_bf16<<<512, 256, 0, stream>>>(w_out, wob, (E * E) / 4);

  gemm_bt<0><<<dim3(3 * E / 128, MR / 128), 256, 0, stream>>>(
      xb, wqkvb, b_qkv, Qb, Kb, Vtb, MR, 3 * E, E);

  attn_fwd4<<<1024, 128, 0, stream>>>(Qb, Kb, Vtb, attnb, causal);

  gemm_bt<1><<<dim3(E / 128, MR / 128), 256, 0, stream>>>(
      attnb, wob, b_out, d_out, nullptr, nullptr, MR, E, E);
}